// Round 5
// baseline (1313.022 us; speedup 1.0000x reference)
//
#include <hip/hip_runtime.h>

// B(derived), IN_DIM=784, NUM_NETS=30, N_NODES=20, NUM_OUT=10, DIM_OUT=16, NUM_ITER=3
// Round-5 strategy: deterministic wrong answer (0.3447, bit-identical across 3
// structurally different rounds) + settled fp32 I/O evidence points at WRONG
// BUFFER BINDING, not math. Fixes: (1) size-based input matching (immune to
// permutation / extra inputs), (2) per-array dtype detector kept (prior dtype
// conclusions void if pointers were shifted), (3) independent naive
// re-implementation of all stages (dodges any latent bug in the tiled kernels).
// ws: h1u[B*600] f32 | flags u32[8]

typedef unsigned short bfu;
typedef unsigned int u32;

__device__ __forceinline__ float bf2f(bfu u) { union { u32 i; float f; } v; v.i = ((u32)u) << 16; return v.f; }
__device__ __forceinline__ float ldf(const void* p, int idx, bool b16) {
    return b16 ? bf2f(((const bfu*)p)[idx]) : ((const float*)p)[idx];
}

// ---- dtype detector: low-ushort-as-bf16 exponent statistic over 64 words ----
// bf16 array: low ushort IS a bf16 -> exponent field in [64,140] for ~all words.
// fp32 array: those bits are mantissa bits -> ~30% in range. Threshold 48/64.
__global__ void detect_dtype(const u32* x, const u32* W1, const u32* b1,
                             const u32* W2, const u32* b2, const u32* rw,
                             u32* flags) {
    int t = threadIdx.x;
    if (t >= 6) return;
    const u32* p = (t == 0) ? x : (t == 1) ? W1 : (t == 2) ? b1
                 : (t == 3) ? W2 : (t == 4) ? b2 : rw;
    int c = 0;
    for (int i = 0; i < 64; i++) {
        u32 e = (p[i] >> 7) & 0xFF;
        c += (e >= 64 && e <= 140) ? 1 : 0;
    }
    flags[t] = (c >= 48) ? 1u : 0u;
}

// ---------------- K1n: h1[b,c] = relu(sum_i x[b,i]*W1[n,i,o] + b1[c]), c=n*20+o ----------
__global__ __launch_bounds__(640) void k1n(const void* x, const void* W1, const void* b1,
                                           float* __restrict__ h1, const u32* flags) {
    __shared__ float xs[784];
    const bool xb = flags[0] != 0, wb = flags[1] != 0, fb = flags[2] != 0;
    const int b = blockIdx.x;
    const int tid = threadIdx.x;
    for (int i = tid; i < 784; i += 640) xs[i] = ldf(x, b * 784 + i, xb);
    __syncthreads();
    if (tid >= 600) return;
    const int n = tid / 20, o = tid - n * 20;
    float acc = ldf(b1, tid, fb);
    const int base = n * 15680 + o;
    for (int i = 0; i < 784; i++) acc += xs[i] * ldf(W1, base + i * 20, wb);
    h1[(size_t)b * 600 + tid] = fmaxf(acc, 0.f);
}

// ---------------- K2n: u = squash_d(relu(h1 @ W2 + b2)) per (b,n), in place ----------------
__global__ __launch_bounds__(256) void k2n(const float* h1, const void* W2, const void* b2,
                                           float* u, const u32* flags, int total) {
    const bool wb = flags[3] != 0, bb = flags[4] != 0;
    int t = blockIdx.x * 256 + threadIdx.x;
    if (t >= total) return;          // t = b*30 + n
    const int b = t / 30, n = t - b * 30;
    const float* hp = h1 + (size_t)b * 600 + n * 20;
    float h[20];
    for (int d = 0; d < 20; d++) h[d] = hp[d];
    float o[20];
    float sq = 0.f;
    for (int e = 0; e < 20; e++) {
        float acc = ldf(b2, n * 20 + e, bb);
        for (int d = 0; d < 20; d++) acc += h[d] * ldf(W2, n * 400 + d * 20 + e, wb);
        acc = fmaxf(acc, 0.f);
        o[e] = acc;
        sq += acc * acc;
    }
    float sc = (sq > 0.f) ? sqrtf(sq) / (1.f + sq) : 0.f;   // squash: t*sqrt(sq)/(1+sq)
    float* up = u + (size_t)b * 600 + n * 20;
    for (int e = 0; e < 20; e++) up[e] = o[e] * sc;
}

// ---------------- K3n: priors + 3-iter routing; one b per 160-thread block ----------------
// thread = (o,k), o in 0..9, k in 0..15. Everything through LDS, no shfl.
__global__ __launch_bounds__(160) void k3n(const float* __restrict__ u, const void* rw,
                                           float* __restrict__ out, const u32* flags) {
    const bool rb = flags[5] != 0;
    __shared__ float PL[30][160];    // priors[n][o*16+k]
    __shared__ float S[160];         // pre-squash s[o][k]
    __shared__ float V[160];         // v[o][k]
    __shared__ float L[300];         // logits[n*10+o]
    __shared__ float M[30], INV[30];
    const int b = blockIdx.x, tid = threadIdx.x;
    const int o = tid >> 4, k = tid & 15;
    const float* ub = u + (size_t)b * 600;

    float pr[30];
    for (int n = 0; n < 30; n++) {
        float acc = 0.f;
        const int base = o * 9600 + n * 320 + k;      // rw[o][n][d][k]
        for (int d = 0; d < 20; d++) acc += ub[n * 20 + d] * ldf(rw, base + d * 16, rb);
        pr[n] = acc;
        PL[n][tid] = acc;
    }
    for (int i = tid; i < 300; i += 160) L[i] = 0.f;
    __syncthreads();

    float v = 0.f;
    for (int it = 0; it < 3; it++) {
        float s = 0.f;
        if (it == 0) {
            for (int n = 0; n < 30; n++) s += pr[n];
            s *= 0.1f;                                 // softmax(0) over 10 outputs
        } else {
            for (int n = 0; n < 30; n++)
                s += __expf(L[n * 10 + o] - M[n]) * INV[n] * pr[n];
        }
        S[tid] = s;
        __syncthreads();
        float sq = 0.f;
        for (int kk = 0; kk < 16; kk++) { float t = S[(o << 4) + kk]; sq += t * t; }
        v = s * sqrtf(sq) / (1.f + sq);
        V[tid] = v;
        __syncthreads();
        if (it < 2) {
            for (int i = tid; i < 300; i += 160) {     // i = n*10+oo
                int n = i / 10, oo = i - n * 10;
                float d = 0.f;
                for (int kk = 0; kk < 16; kk++) d += PL[n][(oo << 4) + kk] * V[(oo << 4) + kk];
                L[i] += d;
            }
            __syncthreads();
            if (tid < 30) {
                float mx = -1e30f;
                for (int oo = 0; oo < 10; oo++) mx = fmaxf(mx, L[tid * 10 + oo]);
                float den = 0.f;
                for (int oo = 0; oo < 10; oo++) den += __expf(L[tid * 10 + oo] - mx);
                M[tid] = mx;
                INV[tid] = 1.f / den;
            }
            __syncthreads();
        }
    }
    out[(size_t)b * 160 + tid] = v;
}

extern "C" void kernel_launch(void* const* d_in, const int* in_sizes, int n_in,
                              void* d_out, int out_size, void* d_ws, size_t ws_size,
                              hipStream_t stream) {
    // ---- size-based input matching (robust to permutation / extra inputs) ----
    int ix = -1, iw1 = -1, ib1 = -1, iw2 = -1, ib2 = -1, irw = -1;
    for (int i = 0; i < n_in; i++) {
        int s = in_sizes[i];
        if (s == 470400 && iw1 < 0) iw1 = i;
        else if (s == 12000 && iw2 < 0) iw2 = i;
        else if (s == 96000 && irw < 0) irw = i;
        else if (s == 600) { if (ib1 < 0) ib1 = i; else if (ib2 < 0) ib2 = i; }
    }
    long bestsz = -1;
    for (int i = 0; i < n_in; i++) {
        if (i == iw1 || i == iw2 || i == irw || i == ib1 || i == ib2) continue;
        if ((long)in_sizes[i] > bestsz) { bestsz = in_sizes[i]; ix = i; }
    }
    if (ix < 0 || iw1 < 0 || ib1 < 0 || iw2 < 0 || ib2 < 0 || irw < 0) {
        ix = 0; iw1 = 1; ib1 = 2; iw2 = 3; ib2 = 4; irw = 5;   // positional fallback
    }
    const void* x  = d_in[ix];
    const void* W1 = d_in[iw1];
    const void* b1 = d_in[ib1];
    const void* W2 = d_in[iw2];
    const void* b2 = d_in[ib2];
    const void* rw = d_in[irw];
    const int B = in_sizes[ix] / 784;
    float* out = (float*)d_out;

    float* ws = (float*)d_ws;
    float* h1u = ws;                               // B*600 floats
    u32* flags = (u32*)(ws + (size_t)B * 600);     // 8 u32

    detect_dtype<<<1, 64, 0, stream>>>((const u32*)x, (const u32*)W1, (const u32*)b1,
                                       (const u32*)W2, (const u32*)b2, (const u32*)rw, flags);
    k1n<<<B, 640, 0, stream>>>(x, W1, b1, h1u, flags);
    k2n<<<(B * 30 + 255) / 256, 256, 0, stream>>>(h1u, W2, b2, h1u, flags, B * 30);
    k3n<<<B, 160, 0, stream>>>(h1u, rw, out, flags);
}

// Round 7
// 649.957 us; speedup vs baseline: 2.0202x; 2.0202x over previous
//
#include <hip/hip_runtime.h>

// B(derived), IN_DIM=784, NUM_NETS=30, N_NODES=20, NUM_OUT=10, DIM_OUT=16, NUM_ITER=3
// ROUND-7 BISECTION: round 5 (naive k1n/k2n/k3n) PASSED; round 6 (all-tiled)
// FAILED bit-identical 0.3447 with identical binding => bug is IN the tiled
// kernels, not the binding. This round swaps ONLY k1: tiled k1_gemm + verbatim
// round-5 k2n/k3n. PASS => bug in tiled k2/k3; FAIL => bug in k1_gemm.
// ws: h1u[B*600] f32 | flags u32[8]

typedef unsigned short bfu;
typedef unsigned int u32;

__device__ __forceinline__ float bf2f(bfu u) { union { u32 i; float f; } v; v.i = ((u32)u) << 16; return v.f; }
__device__ __forceinline__ float lo2f(u32 w) { union { u32 i; float f; } v; v.i = w << 16; return v.f; }
__device__ __forceinline__ float hi2f(u32 w) { union { u32 i; float f; } v; v.i = w & 0xffff0000u; return v.f; }
__device__ __forceinline__ float ldf(const void* p, int idx, bool b16) {
    return b16 ? bf2f(((const bfu*)p)[idx]) : ((const float*)p)[idx];
}

// ---- dtype detector (verbatim round 5) ----
__global__ void detect_dtype(const u32* x, const u32* W1, const u32* b1,
                             const u32* W2, const u32* b2, const u32* rw,
                             u32* flags) {
    int t = threadIdx.x;
    if (t >= 6) return;
    const u32* p = (t == 0) ? x : (t == 1) ? W1 : (t == 2) ? b1
                 : (t == 3) ? W2 : (t == 4) ? b2 : rw;
    int c = 0;
    for (int i = 0; i < 64; i++) {
        u32 e = (p[i] >> 7) & 0xFF;
        c += (e >= 64 && e <= 140) ? 1 : 0;
    }
    flags[t] = (c >= 48) ? 1u : 0u;
}

// ---------------- K1 (tiled, under test): h1 = relu(x @ W1^T-view + b1) ----------------
// 64x64 tile, 1 wave/block, 8x8 micro-tile, BK=16, fp32 accumulate.
// B[k][c] = W1[n][k][o], c = n*20+o; o%4==0 so 4-elem loads never straddle a net.
template<bool XB, bool WB>
__device__ __forceinline__ void k1_body(const void* xv, const void* W1v, const void* b1v,
                                        bool FB, float* __restrict__ h1, int Btot,
                                        float (*As)[64], float (*Bs)[68]) {
    const int lane = threadIdx.x;
    const int m0 = blockIdx.x * 64;
    const int c0 = blockIdx.y * 64;

    float acc[8][8];
    #pragma unroll
    for (int i = 0; i < 8; i++)
        #pragma unroll
        for (int j = 0; j < 8; j++) acc[i][j] = 0.f;

    const int kk = lane >> 2;            // 0..15
    const int cc = (lane & 3) * 16;      // 0/16/32/48

    int  cidx[4];
    bool cval[4];
    #pragma unroll
    for (int j = 0; j < 4; j++) {
        int c = c0 + cc + j * 4;
        cval[j] = (c < 600);
        int cs = cval[j] ? c : 0;
        int n = cs / 20, o = cs - n * 20;
        cidx[j] = n * (784 * 20) + o;
    }
    int mrow = m0 + lane; if (mrow >= Btot) mrow = Btot - 1;
    const size_t xrow = (size_t)mrow * 784;

    for (int k0 = 0; k0 < 784; k0 += 16) {
        float av[16];
        if (XB) {
            const uint4* p = (const uint4*)((const bfu*)xv + xrow + k0);
            uint4 q0 = p[0], q1 = p[1];
            av[0]=lo2f(q0.x); av[1]=hi2f(q0.x); av[2]=lo2f(q0.y); av[3]=hi2f(q0.y);
            av[4]=lo2f(q0.z); av[5]=hi2f(q0.z); av[6]=lo2f(q0.w); av[7]=hi2f(q0.w);
            av[8]=lo2f(q1.x); av[9]=hi2f(q1.x); av[10]=lo2f(q1.y); av[11]=hi2f(q1.y);
            av[12]=lo2f(q1.z); av[13]=hi2f(q1.z); av[14]=lo2f(q1.w); av[15]=hi2f(q1.w);
        } else {
            const float4* p = (const float4*)((const float*)xv + xrow + k0);
            float4 a0 = p[0], a1 = p[1], a2 = p[2], a3 = p[3];
            av[0]=a0.x; av[1]=a0.y; av[2]=a0.z; av[3]=a0.w;
            av[4]=a1.x; av[5]=a1.y; av[6]=a1.z; av[7]=a1.w;
            av[8]=a2.x; av[9]=a2.y; av[10]=a2.z; av[11]=a2.w;
            av[12]=a3.x; av[13]=a3.y; av[14]=a3.z; av[15]=a3.w;
        }
        const int krow = (k0 + kk) * 20;
        float bvv[4][4];
        #pragma unroll
        for (int j = 0; j < 4; j++) {
            if (cval[j]) {
                if (WB) {
                    uint2 w = *(const uint2*)((const bfu*)W1v + cidx[j] + krow);
                    bvv[j][0] = lo2f(w.x); bvv[j][1] = hi2f(w.x);
                    bvv[j][2] = lo2f(w.y); bvv[j][3] = hi2f(w.y);
                } else {
                    float4 f = *(const float4*)((const float*)W1v + cidx[j] + krow);
                    bvv[j][0] = f.x; bvv[j][1] = f.y; bvv[j][2] = f.z; bvv[j][3] = f.w;
                }
            } else {
                bvv[j][0] = bvv[j][1] = bvv[j][2] = bvv[j][3] = 0.f;
            }
        }

        __syncthreads();
        #pragma unroll
        for (int j = 0; j < 16; j++) As[j][lane] = av[j];
        #pragma unroll
        for (int j = 0; j < 4; j++)
            *(float4*)&Bs[kk][cc + j * 4] = *(float4*)bvv[j];
        __syncthreads();

        const int mg = (lane >> 3) * 8, cg = (lane & 7) * 8;
        #pragma unroll
        for (int t = 0; t < 16; t++) {
            float4 av0 = *(const float4*)&As[t][mg];
            float4 av1 = *(const float4*)&As[t][mg + 4];
            float4 bw0 = *(const float4*)&Bs[t][cg];
            float4 bw1 = *(const float4*)&Bs[t][cg + 4];
            float a[8]  = {av0.x, av0.y, av0.z, av0.w, av1.x, av1.y, av1.z, av1.w};
            float bb[8] = {bw0.x, bw0.y, bw0.z, bw0.w, bw1.x, bw1.y, bw1.z, bw1.w};
            #pragma unroll
            for (int i = 0; i < 8; i++)
                #pragma unroll
                for (int j = 0; j < 8; j++) acc[i][j] += a[i] * bb[j];
        }
    }

    const int mg = (lane >> 3) * 8, cg = (lane & 7) * 8;
    #pragma unroll
    for (int i = 0; i < 8; i++) {
        int row = m0 + mg + i;
        if (row >= Btot) continue;
        #pragma unroll
        for (int j4 = 0; j4 < 8; j4 += 4) {
            int c = c0 + cg + j4;
            if (c < 600) {
                float4 r;
                r.x = fmaxf(acc[i][j4 + 0] + ldf(b1v, c + 0, FB), 0.f);
                r.y = fmaxf(acc[i][j4 + 1] + ldf(b1v, c + 1, FB), 0.f);
                r.z = fmaxf(acc[i][j4 + 2] + ldf(b1v, c + 2, FB), 0.f);
                r.w = fmaxf(acc[i][j4 + 3] + ldf(b1v, c + 3, FB), 0.f);
                *(float4*)(h1 + (size_t)row * 600 + c) = r;
            }
        }
    }
}

__global__ __launch_bounds__(64, 4) void k1_gemm(const void* x, const void* W1, const void* b1,
                                                 float* __restrict__ h1, const u32* flags, int Btot) {
    __shared__ float As[16][64];
    __shared__ float Bs[16][68];
    bool xb = flags[0] != 0, wb = flags[1] != 0, fb = flags[2] != 0;
    if (xb) {
        if (wb) k1_body<true,  true >(x, W1, b1, fb, h1, Btot, As, Bs);
        else    k1_body<true,  false>(x, W1, b1, fb, h1, Btot, As, Bs);
    } else {
        if (wb) k1_body<false, true >(x, W1, b1, fb, h1, Btot, As, Bs);
        else    k1_body<false, false>(x, W1, b1, fb, h1, Btot, As, Bs);
    }
}

// ---------------- K2n (verbatim round 5, known good) ----------------
__global__ __launch_bounds__(256) void k2n(const float* h1, const void* W2, const void* b2,
                                           float* u, const u32* flags, int total) {
    const bool wb = flags[3] != 0, bb = flags[4] != 0;
    int t = blockIdx.x * 256 + threadIdx.x;
    if (t >= total) return;          // t = b*30 + n
    const int b = t / 30, n = t - b * 30;
    const float* hp = h1 + (size_t)b * 600 + n * 20;
    float h[20];
    for (int d = 0; d < 20; d++) h[d] = hp[d];
    float o[20];
    float sq = 0.f;
    for (int e = 0; e < 20; e++) {
        float acc = ldf(b2, n * 20 + e, bb);
        for (int d = 0; d < 20; d++) acc += h[d] * ldf(W2, n * 400 + d * 20 + e, wb);
        acc = fmaxf(acc, 0.f);
        o[e] = acc;
        sq += acc * acc;
    }
    float sc = (sq > 0.f) ? sqrtf(sq) / (1.f + sq) : 0.f;
    float* up = u + (size_t)b * 600 + n * 20;
    for (int e = 0; e < 20; e++) up[e] = o[e] * sc;
}

// ---------------- K3n (verbatim round 5, known good) ----------------
__global__ __launch_bounds__(160) void k3n(const float* __restrict__ u, const void* rw,
                                           float* __restrict__ out, const u32* flags) {
    const bool rb = flags[5] != 0;
    __shared__ float PL[30][160];
    __shared__ float S[160];
    __shared__ float V[160];
    __shared__ float L[300];
    __shared__ float M[30], INV[30];
    const int b = blockIdx.x, tid = threadIdx.x;
    const int o = tid >> 4, k = tid & 15;
    const float* ub = u + (size_t)b * 600;

    float pr[30];
    for (int n = 0; n < 30; n++) {
        float acc = 0.f;
        const int base = o * 9600 + n * 320 + k;      // rw[o][n][d][k]
        for (int d = 0; d < 20; d++) acc += ub[n * 20 + d] * ldf(rw, base + d * 16, rb);
        pr[n] = acc;
        PL[n][tid] = acc;
    }
    for (int i = tid; i < 300; i += 160) L[i] = 0.f;
    __syncthreads();

    float v = 0.f;
    for (int it = 0; it < 3; it++) {
        float s = 0.f;
        if (it == 0) {
            for (int n = 0; n < 30; n++) s += pr[n];
            s *= 0.1f;
        } else {
            for (int n = 0; n < 30; n++)
                s += __expf(L[n * 10 + o] - M[n]) * INV[n] * pr[n];
        }
        S[tid] = s;
        __syncthreads();
        float sq = 0.f;
        for (int kk = 0; kk < 16; kk++) { float t = S[(o << 4) + kk]; sq += t * t; }
        v = s * sqrtf(sq) / (1.f + sq);
        V[tid] = v;
        __syncthreads();
        if (it < 2) {
            for (int i = tid; i < 300; i += 160) {
                int n = i / 10, oo = i - n * 10;
                float d = 0.f;
                for (int kk = 0; kk < 16; kk++) d += PL[n][(oo << 4) + kk] * V[(oo << 4) + kk];
                L[i] += d;
            }
            __syncthreads();
            if (tid < 30) {
                float mx = -1e30f;
                for (int oo = 0; oo < 10; oo++) mx = fmaxf(mx, L[tid * 10 + oo]);
                float den = 0.f;
                for (int oo = 0; oo < 10; oo++) den += __expf(L[tid * 10 + oo] - mx);
                M[tid] = mx;
                INV[tid] = 1.f / den;
            }
            __syncthreads();
        }
    }
    out[(size_t)b * 160 + tid] = v;
}

extern "C" void kernel_launch(void* const* d_in, const int* in_sizes, int n_in,
                              void* d_out, int out_size, void* d_ws, size_t ws_size,
                              hipStream_t stream) {
    // ---- size-based input matching (verbatim round 5) ----
    int ix = -1, iw1 = -1, ib1 = -1, iw2 = -1, ib2 = -1, irw = -1;
    for (int i = 0; i < n_in; i++) {
        int s = in_sizes[i];
        if (s == 470400 && iw1 < 0) iw1 = i;
        else if (s == 12000 && iw2 < 0) iw2 = i;
        else if (s == 96000 && irw < 0) irw = i;
        else if (s == 600) { if (ib1 < 0) ib1 = i; else if (ib2 < 0) ib2 = i; }
    }
    long bestsz = -1;
    for (int i = 0; i < n_in; i++) {
        if (i == iw1 || i == iw2 || i == irw || i == ib1 || i == ib2) continue;
        if ((long)in_sizes[i] > bestsz) { bestsz = in_sizes[i]; ix = i; }
    }
    if (ix < 0 || iw1 < 0 || ib1 < 0 || iw2 < 0 || ib2 < 0 || irw < 0) {
        ix = 0; iw1 = 1; ib1 = 2; iw2 = 3; ib2 = 4; irw = 5;
    }
    const void* x  = d_in[ix];
    const void* W1 = d_in[iw1];
    const void* b1 = d_in[ib1];
    const void* W2 = d_in[iw2];
    const void* b2 = d_in[ib2];
    const void* rw = d_in[irw];
    const int B = in_sizes[ix] / 784;
    float* out = (float*)d_out;

    float* ws = (float*)d_ws;
    float* h1u = ws;                               // B*600 floats
    u32* flags = (u32*)(ws + (size_t)B * 600);     // 8 u32

    detect_dtype<<<1, 64, 0, stream>>>((const u32*)x, (const u32*)W1, (const u32*)b1,
                                       (const u32*)W2, (const u32*)b2, (const u32*)rw, flags);
    k1_gemm<<<dim3((B + 63) / 64, 10), 64, 0, stream>>>(x, W1, b1, h1u, flags, B);
    k2n<<<(B * 30 + 255) / 256, 256, 0, stream>>>(h1u, W2, b2, h1u, flags, B * 30);
    k3n<<<B, 160, 0, stream>>>(h1u, rw, out, flags);
}

// Round 8
// 554.870 us; speedup vs baseline: 2.3664x; 1.1714x over previous
//
#include <hip/hip_runtime.h>

// B(derived), IN_DIM=784, NUM_NETS=30, N_NODES=20, NUM_OUT=10, DIM_OUT=16, NUM_ITER=3
// Locked in: size-based binding; device dtype detection; k1_gemm (tiled) correct;
// k2n correct; round-1..6 bug lives in old tiled k2_mlp2/k3_route/prep_rw (discarded).
// This round: k1 -> bf16 MFMA (16x16x32), k3 -> fresh register-resident rewrite.
// ws: h1u[B*600] f32 | rwt[96000] f32 | b1f[640] f32 | flags[8] u32 | Wt[640*800] bf16

typedef unsigned short bfu;
typedef unsigned int u32;
typedef __attribute__((ext_vector_type(8))) short short8;   // 8 bf16 = 4 VGPRs (A/B frag)
typedef __attribute__((ext_vector_type(4))) float floatx4;  // C/D frag

__device__ __forceinline__ float bf2f(bfu u) { union { u32 i; float f; } v; v.i = ((u32)u) << 16; return v.f; }
__device__ __forceinline__ float ldf(const void* p, int idx, bool b16) {
    return b16 ? bf2f(((const bfu*)p)[idx]) : ((const float*)p)[idx];
}
__device__ __forceinline__ bfu f2bf(float f) {   // RNE
    u32 u = __float_as_uint(f);
    return (bfu)((u + 0x7FFFu + ((u >> 16) & 1u)) >> 16);
}

// ---- dtype detector (verbatim, validated) ----
__global__ void detect_dtype(const u32* x, const u32* W1, const u32* b1,
                             const u32* W2, const u32* b2, const u32* rw,
                             u32* flags) {
    int t = threadIdx.x;
    if (t >= 6) return;
    const u32* p = (t == 0) ? x : (t == 1) ? W1 : (t == 2) ? b1
                 : (t == 3) ? W2 : (t == 4) ? b2 : rw;
    int c = 0;
    for (int i = 0; i < 64; i++) {
        u32 e = (p[i] >> 7) & 0xFF;
        c += (e >= 64 && e <= 140) ? 1 : 0;
    }
    flags[t] = (c >= 48) ? 1u : 0u;
}

// ---- prep: W1[n][k][o] -> Wt[c][k] bf16, c=n*20+o, padded to 640x800 with zeros ----
__global__ void prep_wt(const void* W1, bfu* __restrict__ Wt, const u32* flags) {
    const bool wb = flags[1] != 0;
    int idx = blockIdx.x * 256 + threadIdx.x;
    if (idx >= 640 * 800) return;
    int c = idx / 800, k = idx - c * 800;
    bfu v = 0;
    if (c < 600 && k < 784) {
        int nn = c / 20, o = c - nn * 20;
        int src = nn * 15680 + k * 20 + o;
        v = wb ? ((const bfu*)W1)[src] : f2bf(((const float*)W1)[src]);
    }
    Wt[idx] = v;
}

// ---- prep: b1 -> fp32[640] (zero pad) ----
__global__ void prep_b1(const void* b1, float* __restrict__ b1f, const u32* flags) {
    int i = threadIdx.x;
    if (i >= 640) return;
    b1f[i] = (i < 600) ? ldf(b1, i, flags[2] != 0) : 0.f;
}

// ---- prep: rw[o][n][d][k] -> rwt[o][n][k][d] fp32 (fresh rewrite) ----
__global__ void prep_rwt(const void* rw, float* __restrict__ rwt, const u32* flags) {
    const bool rb = flags[5] != 0;
    int idx = blockIdx.x * 256 + threadIdx.x;
    if (idx >= 96000) return;
    int d = idx % 20;
    int k = (idx / 20) % 16;
    int n = (idx / 320) % 30;
    int o = idx / 9600;
    rwt[idx] = ldf(rw, o * 9600 + n * 320 + d * 16 + k, rb);
}

// ---------------- K1m: h1 = relu(x @ Wt^T + b1), bf16 MFMA ----------------
// Block 256 thr = 4 waves; block tile M128 x N64; wave tile 32x64; BK=32.
// A-frag: A[m=lane&15][k=quad*8+j]; B-frag: B[k=quad*8+j][n=lane&15];
// D: row=quad*4+reg, col=lane&15  (guide-verified layouts, m89/m91/m120).
template<bool XB>
__device__ __forceinline__ void k1m_body(const void* xv, const bfu* __restrict__ Wt,
                                         const float* __restrict__ b1f,
                                         float* __restrict__ h1, int Btot,
                                         short* As, short* Bs) {
    const int tid = threadIdx.x;
    const int w = tid >> 6, lane = tid & 63;
    const int quad = lane >> 4, fl = lane & 15;
    const int m0 = blockIdx.x * 128, n0 = blockIdx.y * 64;

    floatx4 acc[2][4];
    #pragma unroll
    for (int mi = 0; mi < 2; mi++)
        #pragma unroll
        for (int ni = 0; ni < 4; ni++) acc[mi][ni] = (floatx4){0.f, 0.f, 0.f, 0.f};

    // staging roles
    const int arow = tid >> 1, aseg = tid & 1;   // A: 128 rows x 2 segs of 16 bf16
    const int brow = tid >> 2, bseg = tid & 3;   // B: 64 rows x 4 segs of 8 bf16
    int agrow = m0 + arow; if (agrow >= Btot) agrow = Btot - 1;

    for (int k0 = 0; k0 < 800; k0 += 32) {
        // --- stage A (x row -> bf16), zero-pad k>=784 ---
        bfu av[16];
        const int kbase = k0 + aseg * 16;
        if (kbase < 784) {               // [kbase,kbase+16) fully valid (784 = seg-aligned)
            if (XB) {
                const uint4* p = (const uint4*)((const bfu*)xv + (size_t)agrow * 784 + kbase);
                uint4 q0 = p[0], q1 = p[1];
                *(uint4*)&av[0] = q0; *(uint4*)&av[8] = q1;
            } else {
                const float4* p = (const float4*)((const float*)xv + (size_t)agrow * 784 + kbase);
                #pragma unroll
                for (int q = 0; q < 4; q++) {
                    float4 f = p[q];
                    av[q * 4 + 0] = f2bf(f.x); av[q * 4 + 1] = f2bf(f.y);
                    av[q * 4 + 2] = f2bf(f.z); av[q * 4 + 3] = f2bf(f.w);
                }
            }
        } else {
            #pragma unroll
            for (int q = 0; q < 16; q++) av[q] = 0;
        }
        // --- stage B (Wt pre-padded) ---
        uint4 bv = *(const uint4*)(Wt + (size_t)(n0 + brow) * 800 + k0 + bseg * 8);

        __syncthreads();   // protect LDS from previous iteration's readers
        *(uint4*)&As[arow * 40 + aseg * 16 + 0] = *(uint4*)&av[0];
        *(uint4*)&As[arow * 40 + aseg * 16 + 8] = *(uint4*)&av[8];
        *(uint4*)&Bs[brow * 40 + bseg * 8] = bv;
        __syncthreads();

        // --- compute ---
        short8 af[2], bf[4];
        #pragma unroll
        for (int mi = 0; mi < 2; mi++)
            af[mi] = *(const short8*)&As[(w * 32 + mi * 16 + fl) * 40 + quad * 8];
        #pragma unroll
        for (int ni = 0; ni < 4; ni++)
            bf[ni] = *(const short8*)&Bs[(ni * 16 + fl) * 40 + quad * 8];
        #pragma unroll
        for (int mi = 0; mi < 2; mi++)
            #pragma unroll
            for (int ni = 0; ni < 4; ni++)
                acc[mi][ni] = __builtin_amdgcn_mfma_f32_16x16x32_bf16(af[mi], bf[ni], acc[mi][ni], 0, 0, 0);
    }

    // --- epilogue: D row=quad*4+r, col=fl ---
    #pragma unroll
    for (int mi = 0; mi < 2; mi++) {
        #pragma unroll
        for (int ni = 0; ni < 4; ni++) {
            const int c = n0 + ni * 16 + fl;
            #pragma unroll
            for (int r = 0; r < 4; r++) {
                const int m = m0 + w * 32 + mi * 16 + quad * 4 + r;
                if (c < 600 && m < Btot)
                    h1[(size_t)m * 600 + c] = fmaxf(acc[mi][ni][r] + b1f[c], 0.f);
            }
        }
    }
}

__global__ __launch_bounds__(256, 2) void k1m(const void* xv, const bfu* __restrict__ Wt,
                                              const float* __restrict__ b1f,
                                              float* __restrict__ h1, const u32* flags, int Btot) {
    __shared__ short As[128 * 40];   // row stride 40 bf16 (80 B) -> 2-way conflicts only
    __shared__ short Bs[64 * 40];
    if (flags[0] != 0) k1m_body<true >(xv, Wt, b1f, h1, Btot, As, Bs);
    else               k1m_body<false>(xv, Wt, b1f, h1, Btot, As, Bs);
}

// ---------------- K2n (verbatim, validated twice) ----------------
__global__ __launch_bounds__(256) void k2n(const float* h1, const void* W2, const void* b2,
                                           float* u, const u32* flags, int total) {
    const bool wb = flags[3] != 0, bb = flags[4] != 0;
    int t = blockIdx.x * 256 + threadIdx.x;
    if (t >= total) return;          // t = b*30 + n
    const int b = t / 30, n = t - b * 30;
    const float* hp = h1 + (size_t)b * 600 + n * 20;
    float h[20];
    for (int d = 0; d < 20; d++) h[d] = hp[d];
    float o[20];
    float sq = 0.f;
    for (int e = 0; e < 20; e++) {
        float acc = ldf(b2, n * 20 + e, bb);
        for (int d = 0; d < 20; d++) acc += h[d] * ldf(W2, n * 400 + d * 20 + e, wb);
        acc = fmaxf(acc, 0.f);
        o[e] = acc;
        sq += acc * acc;
    }
    float sc = (sq > 0.f) ? sqrtf(sq) / (1.f + sq) : 0.f;
    float* up = u + (size_t)b * 600 + n * 20;
    for (int e = 0; e < 20; e++) up[e] = o[e] * sc;
}

// ---------------- K3v: priors + routing, fresh rewrite ----------------
// Block 512 thr, 4 batches/block. Active tid<480: (n=tid>>4, k=tid&15).
// priors[g][o] in VGPRs; rwt float4 loads amortized over 4 batches;
// softmax over o in-register; squash/delta via LDS + shfl(width 16).
__global__ __launch_bounds__(512, 2) void k3v(const float* __restrict__ u,
                                              const float* __restrict__ rwt,
                                              float* __restrict__ out, int Btot) {
    __shared__ float SP[30 * 164];   // [n][o*16+k], stride 164 spreads banks
    __shared__ float V[160];
    const int tid = threadIdx.x;
    const bool act = tid < 480;
    const int n = tid >> 4, k = tid & 15;
    const int b0 = blockIdx.x * 4;

    float pri[4][10];
    #pragma unroll
    for (int g = 0; g < 4; g++)
        #pragma unroll
        for (int o = 0; o < 10; o++) pri[g][o] = 0.f;

    if (act) {
        #pragma unroll
        for (int d4 = 0; d4 < 5; d4++) {
            float4 uu[4];
            #pragma unroll
            for (int g = 0; g < 4; g++) {
                int b = b0 + g; if (b >= Btot) b = Btot - 1;
                uu[g] = *(const float4*)(u + (size_t)b * 600 + n * 20 + d4 * 4);
            }
            #pragma unroll
            for (int o = 0; o < 10; o++) {
                float4 rv = *(const float4*)(rwt + (size_t)((o * 30 + n) * 16 + k) * 20 + d4 * 4);
                #pragma unroll
                for (int g = 0; g < 4; g++)
                    pri[g][o] += rv.x * uu[g].x + rv.y * uu[g].y + rv.z * uu[g].z + rv.w * uu[g].w;
            }
        }
    }

    for (int g = 0; g < 4; g++) {
        const int b = b0 + g;
        float logits[10];
        #pragma unroll
        for (int o = 0; o < 10; o++) logits[o] = 0.f;

        for (int it = 0; it < 3; it++) {
            __syncthreads();   // protect SP/V reuse
            if (act) {
                float mx = logits[0];
                #pragma unroll
                for (int o = 1; o < 10; o++) mx = fmaxf(mx, logits[o]);
                float e[10], den = 0.f;
                #pragma unroll
                for (int o = 0; o < 10; o++) { e[o] = __expf(logits[o] - mx); den += e[o]; }
                float inv = 1.f / den;
                #pragma unroll
                for (int o = 0; o < 10; o++)
                    SP[n * 164 + o * 16 + k] = e[o] * inv * pri[g][o];
            }
            __syncthreads();
            if (tid < 160) {   // (o=tid>>4, k=tid&15): s = sum_n, squash over k
                float s = 0.f;
                #pragma unroll
                for (int nn = 0; nn < 30; nn++) s += SP[nn * 164 + tid];
                float sq = s * s;
                sq += __shfl_xor(sq, 1, 16);
                sq += __shfl_xor(sq, 2, 16);
                sq += __shfl_xor(sq, 4, 16);
                sq += __shfl_xor(sq, 8, 16);
                float v = s * sqrtf(sq) / (1.f + sq);
                V[tid] = v;
                if (it == 2 && b < Btot) out[(size_t)b * 160 + tid] = v;
            }
            __syncthreads();
            if (it < 2 && act) {
                float t[10];
                #pragma unroll
                for (int o = 0; o < 10; o++) t[o] = pri[g][o] * V[o * 16 + k];
                #pragma unroll
                for (int mask = 1; mask < 16; mask <<= 1)
                    #pragma unroll
                    for (int o = 0; o < 10; o++) t[o] += __shfl_xor(t[o], mask, 16);
                #pragma unroll
                for (int o = 0; o < 10; o++) logits[o] += t[o];
            }
        }
    }
}

extern "C" void kernel_launch(void* const* d_in, const int* in_sizes, int n_in,
                              void* d_out, int out_size, void* d_ws, size_t ws_size,
                              hipStream_t stream) {
    // ---- size-based input matching (validated) ----
    int ix = -1, iw1 = -1, ib1 = -1, iw2 = -1, ib2 = -1, irw = -1;
    for (int i = 0; i < n_in; i++) {
        int s = in_sizes[i];
        if (s == 470400 && iw1 < 0) iw1 = i;
        else if (s == 12000 && iw2 < 0) iw2 = i;
        else if (s == 96000 && irw < 0) irw = i;
        else if (s == 600) { if (ib1 < 0) ib1 = i; else if (ib2 < 0) ib2 = i; }
    }
    long bestsz = -1;
    for (int i = 0; i < n_in; i++) {
        if (i == iw1 || i == iw2 || i == irw || i == ib1 || i == ib2) continue;
        if ((long)in_sizes[i] > bestsz) { bestsz = in_sizes[i]; ix = i; }
    }
    if (ix < 0 || iw1 < 0 || ib1 < 0 || iw2 < 0 || ib2 < 0 || irw < 0) {
        ix = 0; iw1 = 1; ib1 = 2; iw2 = 3; ib2 = 4; irw = 5;
    }
    const void* x  = d_in[ix];
    const void* W1 = d_in[iw1];
    const void* b1 = d_in[ib1];
    const void* W2 = d_in[iw2];
    const void* b2 = d_in[ib2];
    const void* rw = d_in[irw];
    const int B = in_sizes[ix] / 784;
    float* out = (float*)d_out;

    float* ws   = (float*)d_ws;
    float* h1u  = ws;                                  // B*600 f32
    float* rwt  = ws + (size_t)B * 600;                // 96000 f32
    float* b1f  = rwt + 96000;                         // 640 f32
    u32*   flags = (u32*)(b1f + 640);                  // 8 u32
    bfu*   Wt   = (bfu*)(flags + 8);                   // 640*800 bf16 (16B-aligned)

    detect_dtype<<<1, 64, 0, stream>>>((const u32*)x, (const u32*)W1, (const u32*)b1,
                                       (const u32*)W2, (const u32*)b2, (const u32*)rw, flags);
    prep_wt<<<(640 * 800 + 255) / 256, 256, 0, stream>>>(W1, Wt, flags);
    prep_b1<<<1, 640, 0, stream>>>(b1, b1f, flags);
    prep_rwt<<<(96000 + 255) / 256, 256, 0, stream>>>(rw, rwt, flags);
    k1m<<<dim3((B + 127) / 128, 10), 256, 0, stream>>>(x, Wt, b1f, h1u, flags, B);
    k2n<<<(B * 30 + 255) / 256, 256, 0, stream>>>(h1u, W2, b2, h1u, flags, B * 30);
    k3v<<<(B + 3) / 4, 512, 0, stream>>>(h1u, rwt, out, B);
}

// Round 9
// 491.952 us; speedup vs baseline: 2.6690x; 1.1279x over previous
//
#include <hip/hip_runtime.h>

// B(derived), IN_DIM=784, NUM_NETS=30, N_NODES=20, NUM_OUT=10, DIM_OUT=16, NUM_ITER=3
// Validated: size-based binding; device dtype detection; k1m (MFMA) / k2n / k3v math.
// R9: k3 parallel-g restructure (36 barriers -> 6), x pre-cast to bf16 for k1m,
// k2 LDS-staged W2. ws: h1u[B*600] f32 | rwt[96000] f32 | b1f[640] f32 | flags[8]
//                      | Wt[640*800] bf16 | xb[B*800] bf16

typedef unsigned short bfu;
typedef unsigned int u32;
typedef __attribute__((ext_vector_type(8))) short short8;   // 8 bf16 (A/B frag)
typedef __attribute__((ext_vector_type(4))) float floatx4;  // C/D frag

__device__ __forceinline__ float bf2f(bfu u) { union { u32 i; float f; } v; v.i = ((u32)u) << 16; return v.f; }
__device__ __forceinline__ float ldf(const void* p, int idx, bool b16) {
    return b16 ? bf2f(((const bfu*)p)[idx]) : ((const float*)p)[idx];
}
__device__ __forceinline__ bfu f2bf(float f) {   // RNE
    u32 u = __float_as_uint(f);
    return (bfu)((u + 0x7FFFu + ((u >> 16) & 1u)) >> 16);
}

// ---- dtype detector (validated) ----
__global__ void detect_dtype(const u32* x, const u32* W1, const u32* b1,
                             const u32* W2, const u32* b2, const u32* rw,
                             u32* flags) {
    int t = threadIdx.x;
    if (t >= 6) return;
    const u32* p = (t == 0) ? x : (t == 1) ? W1 : (t == 2) ? b1
                 : (t == 3) ? W2 : (t == 4) ? b2 : rw;
    int c = 0;
    for (int i = 0; i < 64; i++) {
        u32 e = (p[i] >> 7) & 0xFF;
        c += (e >= 64 && e <= 140) ? 1 : 0;
    }
    flags[t] = (c >= 48) ? 1u : 0u;
}

// ---- prep: x -> xb[B][800] bf16, zero-padded ----
__global__ void prep_xb(const void* x, bfu* __restrict__ xb, const u32* flags, int total) {
    const bool b16 = flags[0] != 0;
    int idx = blockIdx.x * 256 + threadIdx.x;
    if (idx >= total) return;
    int b = idx / 800, kk = idx - b * 800;
    bfu v = 0;
    if (kk < 784) {
        int src = b * 784 + kk;
        v = b16 ? ((const bfu*)x)[src] : f2bf(((const float*)x)[src]);
    }
    xb[idx] = v;
}

// ---- prep: W1[n][k][o] -> Wt[c][k] bf16, c=n*20+o, padded 640x800 (validated) ----
__global__ void prep_wt(const void* W1, bfu* __restrict__ Wt, const u32* flags) {
    const bool wb = flags[1] != 0;
    int idx = blockIdx.x * 256 + threadIdx.x;
    if (idx >= 640 * 800) return;
    int c = idx / 800, k = idx - c * 800;
    bfu v = 0;
    if (c < 600 && k < 784) {
        int nn = c / 20, o = c - nn * 20;
        int src = nn * 15680 + k * 20 + o;
        v = wb ? ((const bfu*)W1)[src] : f2bf(((const float*)W1)[src]);
    }
    Wt[idx] = v;
}

// ---- prep: b1 -> fp32[640] (validated) ----
__global__ void prep_b1(const void* b1, float* __restrict__ b1f, const u32* flags) {
    int i = threadIdx.x;
    if (i >= 640) return;
    b1f[i] = (i < 600) ? ldf(b1, i, flags[2] != 0) : 0.f;
}

// ---- prep: rw[o][n][d][k] -> rwt[o][n][k][d] fp32 (validated) ----
__global__ void prep_rwt(const void* rw, float* __restrict__ rwt, const u32* flags) {
    const bool rb = flags[5] != 0;
    int idx = blockIdx.x * 256 + threadIdx.x;
    if (idx >= 96000) return;
    int d = idx % 20;
    int k = (idx / 20) % 16;
    int n = (idx / 320) % 30;
    int o = idx / 9600;
    rwt[idx] = ldf(rw, o * 9600 + n * 320 + d * 16 + k, rb);
}

// ---------------- K1m: h1 = relu(xb @ Wt^T + b1), bf16 MFMA (validated layouts) ----------------
// Block 256 = 4 waves; tile M128 x N64; wave 32x64; BK=32. xb pre-cast: staging is pure copy.
__global__ __launch_bounds__(256, 4) void k1m(const bfu* __restrict__ xb, const bfu* __restrict__ Wt,
                                              const float* __restrict__ b1f,
                                              float* __restrict__ h1, int Btot) {
    __shared__ short As[128 * 40];   // row stride 40 bf16 -> 2-way only
    __shared__ short Bs[64 * 40];
    const int tid = threadIdx.x;
    const int w = tid >> 6, lane = tid & 63;
    const int quad = lane >> 4, fl = lane & 15;
    const int m0 = blockIdx.x * 128, n0 = blockIdx.y * 64;

    floatx4 acc[2][4];
    #pragma unroll
    for (int mi = 0; mi < 2; mi++)
        #pragma unroll
        for (int ni = 0; ni < 4; ni++) acc[mi][ni] = (floatx4){0.f, 0.f, 0.f, 0.f};

    const int arow = tid >> 1, aseg = tid & 1;   // A: 128 rows x 2 segs of 16 bf16
    const int brow = tid >> 2, bseg = tid & 3;   // B: 64 rows x 4 segs of 8 bf16
    int agrow = m0 + arow; if (agrow >= Btot) agrow = Btot - 1;
    const bfu* abase = xb + (size_t)agrow * 800 + aseg * 16;
    const bfu* bbase = Wt + (size_t)(n0 + brow) * 800 + bseg * 8;

    for (int k0 = 0; k0 < 800; k0 += 32) {
        uint4 qa0 = *(const uint4*)(abase + k0);
        uint4 qa1 = *(const uint4*)(abase + k0 + 8);
        uint4 qb  = *(const uint4*)(bbase + k0);

        __syncthreads();
        *(uint4*)&As[arow * 40 + aseg * 16 + 0] = qa0;
        *(uint4*)&As[arow * 40 + aseg * 16 + 8] = qa1;
        *(uint4*)&Bs[brow * 40 + bseg * 8] = qb;
        __syncthreads();

        short8 af[2], bfr[4];
        #pragma unroll
        for (int mi = 0; mi < 2; mi++)
            af[mi] = *(const short8*)&As[(w * 32 + mi * 16 + fl) * 40 + quad * 8];
        #pragma unroll
        for (int ni = 0; ni < 4; ni++)
            bfr[ni] = *(const short8*)&Bs[(ni * 16 + fl) * 40 + quad * 8];
        #pragma unroll
        for (int mi = 0; mi < 2; mi++)
            #pragma unroll
            for (int ni = 0; ni < 4; ni++)
                acc[mi][ni] = __builtin_amdgcn_mfma_f32_16x16x32_bf16(af[mi], bfr[ni], acc[mi][ni], 0, 0, 0);
    }

    #pragma unroll
    for (int mi = 0; mi < 2; mi++) {
        #pragma unroll
        for (int ni = 0; ni < 4; ni++) {
            const int c = n0 + ni * 16 + fl;
            #pragma unroll
            for (int r = 0; r < 4; r++) {
                const int m = m0 + w * 32 + mi * 16 + quad * 4 + r;
                if (c < 600 && m < Btot)
                    h1[(size_t)m * 600 + c] = fmaxf(acc[mi][ni][r] + b1f[c], 0.f);
            }
        }
    }
}

// ---------------- K2s: u = squash(relu(h1 @ W2 + b2)), LDS-staged W2 ----------------
// Thread map + math identical to validated k2n; W2/b2 via LDS, h/u via float4.
__global__ __launch_bounds__(256) void k2s(const float* h1, const void* W2, const void* b2,
                                           float* u, const u32* flags, int total) {
    __shared__ float W2s[12000];
    __shared__ float b2s[600];
    const bool wb = flags[3] != 0, bb = flags[4] != 0;
    const int tid = threadIdx.x;
    for (int i = tid; i < 12000; i += 256) W2s[i] = ldf(W2, i, wb);
    for (int i = tid; i < 600; i += 256) b2s[i] = ldf(b2, i, bb);
    __syncthreads();

    int t = blockIdx.x * 256 + tid;
    if (t >= total) return;          // t = b*30 + n
    const int b = t / 30, n = t - b * 30;
    const float* hp = h1 + (size_t)b * 600 + n * 20;
    float h[20];
    #pragma unroll
    for (int d4 = 0; d4 < 20; d4 += 4) {
        float4 v = *(const float4*)(hp + d4);
        h[d4] = v.x; h[d4 + 1] = v.y; h[d4 + 2] = v.z; h[d4 + 3] = v.w;
    }
    const float* wn = &W2s[n * 400];
    float o[20];
    float sq = 0.f;
    #pragma unroll
    for (int e = 0; e < 20; e++) {
        float acc = b2s[n * 20 + e];
        #pragma unroll
        for (int d = 0; d < 20; d++) acc += h[d] * wn[d * 20 + e];
        acc = fmaxf(acc, 0.f);
        o[e] = acc;
        sq += acc * acc;
    }
    float sc = (sq > 0.f) ? sqrtf(sq) / (1.f + sq) : 0.f;
    float* up = u + (size_t)b * 600 + n * 20;
    #pragma unroll
    for (int e4 = 0; e4 < 20; e4 += 4) {
        float4 v;
        v.x = o[e4] * sc; v.y = o[e4 + 1] * sc; v.z = o[e4 + 2] * sc; v.w = o[e4 + 3] * sc;
        *(float4*)(up + e4) = v;
    }
}

// ---------------- K3w: priors + routing, all 4 batches in parallel ----------------
// Block 640 thr. Priors/exp/delta: (n,k) threads tid<480, pri[4][10]+lg[4][10] in VGPRs.
// Squash: all 640 threads as (g2=tid/160, r=o*16+k). 6 barriers/block (was 36).
__global__ __launch_bounds__(640) void k3w(const float* __restrict__ u,
                                           const float* __restrict__ rwt,
                                           float* __restrict__ out, int Btot) {
    __shared__ float SP[4 * 5040];   // [g][n*168 + o*16 + k]; stride 168 -> uniform 2-way
    __shared__ float V[4 * 160];
    const int tid = threadIdx.x;
    const bool act = tid < 480;
    const int n = tid >> 4, k = tid & 15;
    const int g2 = tid / 160, r = tid - g2 * 160;
    const int b0 = blockIdx.x * 4;

    // ---- priors (verbatim k3v structure, validated) ----
    float pri[4][10];
    #pragma unroll
    for (int g = 0; g < 4; g++)
        #pragma unroll
        for (int o = 0; o < 10; o++) pri[g][o] = 0.f;

    if (act) {
        #pragma unroll
        for (int d4 = 0; d4 < 5; d4++) {
            float4 uu[4];
            #pragma unroll
            for (int g = 0; g < 4; g++) {
                int b = b0 + g; if (b >= Btot) b = Btot - 1;
                uu[g] = *(const float4*)(u + (size_t)b * 600 + n * 20 + d4 * 4);
            }
            #pragma unroll
            for (int o = 0; o < 10; o++) {
                float4 rv = *(const float4*)(rwt + (size_t)((o * 30 + n) * 16 + k) * 20 + d4 * 4);
                #pragma unroll
                for (int g = 0; g < 4; g++)
                    pri[g][o] += rv.x * uu[g].x + rv.y * uu[g].y + rv.z * uu[g].z + rv.w * uu[g].w;
            }
        }
    }

    float lg[4][10];
    #pragma unroll
    for (int g = 0; g < 4; g++)
        #pragma unroll
        for (int o = 0; o < 10; o++) lg[g][o] = 0.f;

    for (int it = 0; it < 3; it++) {
        // phase 1: softmax(lg) * priors -> SP   (iter0: lg=0 -> uniform 0.1, exact ref math)
        if (act) {
            #pragma unroll
            for (int g = 0; g < 4; g++) {
                float mx = lg[g][0];
                #pragma unroll
                for (int o = 1; o < 10; o++) mx = fmaxf(mx, lg[g][o]);
                float e[10], den = 0.f;
                #pragma unroll
                for (int o = 0; o < 10; o++) { e[o] = __expf(lg[g][o] - mx); den += e[o]; }
                float inv = 1.f / den;
                #pragma unroll
                for (int o = 0; o < 10; o++)
                    SP[g * 5040 + n * 168 + o * 16 + k] = e[o] * inv * pri[g][o];
            }
        }
        __syncthreads();
        // phase 2: s = sum_n SP; squash over k; write V (+ out on last iter)
        {
            float s = 0.f;
            #pragma unroll
            for (int nn = 0; nn < 30; nn++) s += SP[g2 * 5040 + nn * 168 + r];
            float q = s * s;
            q += __shfl_xor(q, 1, 16);
            q += __shfl_xor(q, 2, 16);
            q += __shfl_xor(q, 4, 16);
            q += __shfl_xor(q, 8, 16);
            float v = s * sqrtf(q) / (1.f + q);
            V[g2 * 160 + r] = v;
            if (it == 2 && (b0 + g2) < Btot) out[(size_t)(b0 + g2) * 160 + r] = v;
        }
        __syncthreads();
        // phase 3: lg[g][o] += sum_k pri * v   (shfl-16 butterfly)
        if (it < 2 && act) {
            #pragma unroll
            for (int g = 0; g < 4; g++) {
                float tt[10];
                #pragma unroll
                for (int o = 0; o < 10; o++) tt[o] = pri[g][o] * V[g * 160 + o * 16 + k];
                #pragma unroll
                for (int mask = 1; mask < 16; mask <<= 1)
                    #pragma unroll
                    for (int o = 0; o < 10; o++) tt[o] += __shfl_xor(tt[o], mask, 16);
                #pragma unroll
                for (int o = 0; o < 10; o++) lg[g][o] += tt[o];
            }
        }
    }
}

extern "C" void kernel_launch(void* const* d_in, const int* in_sizes, int n_in,
                              void* d_out, int out_size, void* d_ws, size_t ws_size,
                              hipStream_t stream) {
    // ---- size-based input matching (validated) ----
    int ix = -1, iw1 = -1, ib1 = -1, iw2 = -1, ib2 = -1, irw = -1;
    for (int i = 0; i < n_in; i++) {
        int s = in_sizes[i];
        if (s == 470400 && iw1 < 0) iw1 = i;
        else if (s == 12000 && iw2 < 0) iw2 = i;
        else if (s == 96000 && irw < 0) irw = i;
        else if (s == 600) { if (ib1 < 0) ib1 = i; else if (ib2 < 0) ib2 = i; }
    }
    long bestsz = -1;
    for (int i = 0; i < n_in; i++) {
        if (i == iw1 || i == iw2 || i == irw || i == ib1 || i == ib2) continue;
        if ((long)in_sizes[i] > bestsz) { bestsz = in_sizes[i]; ix = i; }
    }
    if (ix < 0 || iw1 < 0 || ib1 < 0 || iw2 < 0 || ib2 < 0 || irw < 0) {
        ix = 0; iw1 = 1; ib1 = 2; iw2 = 3; ib2 = 4; irw = 5;
    }
    const void* x  = d_in[ix];
    const void* W1 = d_in[iw1];
    const void* b1 = d_in[ib1];
    const void* W2 = d_in[iw2];
    const void* b2 = d_in[ib2];
    const void* rw = d_in[irw];
    const int B = in_sizes[ix] / 784;
    float* out = (float*)d_out;

    float* ws   = (float*)d_ws;
    float* h1u  = ws;                                  // B*600 f32
    float* rwt  = ws + (size_t)B * 600;                // 96000 f32
    float* b1f  = rwt + 96000;                         // 640 f32
    u32*   flags = (u32*)(b1f + 640);                  // 8 u32
    bfu*   Wt   = (bfu*)(flags + 8);                   // 640*800 bf16
    bfu*   xb   = Wt + 640 * 800;                      // B*800 bf16

    detect_dtype<<<1, 64, 0, stream>>>((const u32*)x, (const u32*)W1, (const u32*)b1,
                                       (const u32*)W2, (const u32*)b2, (const u32*)rw, flags);
    prep_xb<<<(B * 800 + 255) / 256, 256, 0, stream>>>(x, xb, flags, B * 800);
    prep_wt<<<(640 * 800 + 255) / 256, 256, 0, stream>>>(W1, Wt, flags);
    prep_b1<<<1, 640, 0, stream>>>(b1, b1f, flags);
    prep_rwt<<<(96000 + 255) / 256, 256, 0, stream>>>(rw, rwt, flags);
    k1m<<<dim3((B + 127) / 128, 10), 256, 0, stream>>>(xb, Wt, b1f, h1u, B);
    k2s<<<(B * 30 + 255) / 256, 256, 0, stream>>>(h1u, W2, b2, h1u, flags, B * 30);
    k3w<<<(B + 3) / 4, 640, 0, stream>>>(h1u, rwt, out, B);
}